// Round 1
// baseline (5006.279 us; speedup 1.0000x reference)
//
#include <hip/hip_runtime.h>
#include <cstdint>
#include <cstddef>

// ============================================================================
// LSTMClassifierQuantized: B=64, S=512, H=E=512, 4H=2048, per-tensor int8
// fake-quant on x_t/h/c/W per step. Sequential over 512 steps with one
// grid barrier per step (global max|h|, max|c| scales force it).
//
// Strategy:
//  - int8 exact GEMM via v_mfma_i32_16x16x64_i8 (|acc| <= 512*127^2 < 2^23,
//    so int accumulate AND int->float are exact; only the final scale mul
//    rounds). x-part and h-part use separate accumulators (different scales).
//  - persistent kernel: 64 blocks x 256 thr (4 waves). Block bk owns hidden
//    units [bk*8, bk*8+8) => 32 gate columns. Wave (mh,nt): row-half mh,
//    16-col tile nt. Weight B-fragments in VGPRs for entire kernel.
//  - h stored fp32 in fragment-major layout (double buffered); every block
//    reloads all h post-barrier and quantizes redundantly into LDS
//    (magic-number fma trick: low mantissa byte == int8 two's complement).
//  - c state lives in registers of its owner thread across all 512 steps.
//  - barrier: __syncthreads -> tid0: __threadfence (wbl2) -> release add ->
//    spin relaxed -> __syncthreads -> acquire fence (buffer_inv). Generation
//    counter monotonic, no resets.
// ============================================================================

typedef int v4i __attribute__((ext_vector_type(4)));

#define NB   64
#define SEQ  512
#define HID  512
#define G4   2048
#define NBLK 64
#define NTHR 256

// workspace byte offsets
#define OFF_CNT     0
#define OFF_SLOT1   64            // u32[4]: wi, wh, lw, hl  (abs-max bits)
#define OFF_SLOTH   128           // u32[513]
#define OFF_SLOTC   2304          // u32[513]
#define OFF_SX      4608          // f32[512] raw max|x_t|
#define OFF_LEN     6912          // i32[64]
#define OFF_HG      7168          // f32[2][64*512] double-buffered h (frag-major)
#define ZERO_BYTES  269312
#define OFF_HLAST   269312        // f32[64*512] row-major
#define OFF_WIF     400384        // v4i[65536] frag-major int8 Wi (1 MB)
#define OFF_WHF     1448960       // v4i[65536]
#define OFF_XF      2497536       // v4i[512*2048] frag-major int8 x (16 MB)
#define WS_NEED     19274752

__device__ __forceinline__ int fragidx(int row, int kq) {
  // 16-byte chunk index for A-operand fragment: lane l of tile (m,kb) holds
  // A[row=m*16+(l&15)][k=kb*64+(l>>4)*16 + 0..15]
  return ((row >> 4) * 8 + (kq >> 2)) * 64 + ((kq & 3) << 4) + (row & 15);
}

__device__ __forceinline__ float sigm(float x) {
  return 1.0f / (1.0f + __expf(-x));
}

// magic-number round-to-nearest-even int8 pack (|x*inv| <= 127)
__device__ __forceinline__ int pack4q(float4 v, float inv) {
  union { float f; unsigned u; } a, b, c, d;
  a.f = __builtin_fmaf(v.x, inv, 12582912.0f);   // 1.5 * 2^23
  b.f = __builtin_fmaf(v.y, inv, 12582912.0f);
  c.f = __builtin_fmaf(v.z, inv, 12582912.0f);
  d.f = __builtin_fmaf(v.w, inv, 12582912.0f);
  return (int)((a.u & 0xffu) | ((b.u & 0xffu) << 8) |
               ((c.u & 0xffu) << 16) | ((d.u & 0xffu) << 24));
}

// exact-IEEE-division quantize pack (setup kernels)
__device__ __forceinline__ unsigned packdiv(const float* p, float s) {
  unsigned r = 0;
#pragma unroll
  for (int j = 0; j < 4; j++) {
    int n = (int)rintf(p[j] / s);
    r |= ((unsigned)n & 0xffu) << (8 * j);
  }
  return r;
}

// ------------------------------- setup kernels ------------------------------

__global__ void k_maxw(const float* __restrict__ wi, const float* __restrict__ wh,
                       const float* __restrict__ lw, unsigned* ws_u) {
  float m1 = 0.f, m2 = 0.f, m3 = 0.f;
  int stride = gridDim.x * blockDim.x;
  int t0 = blockIdx.x * blockDim.x + threadIdx.x;
  for (int i = t0; i < G4 * HID; i += stride) m1 = fmaxf(m1, fabsf(wi[i]));
  for (int i = t0; i < G4 * HID; i += stride) m2 = fmaxf(m2, fabsf(wh[i]));
  for (int i = t0; i < HID; i += stride)      m3 = fmaxf(m3, fabsf(lw[i]));
#pragma unroll
  for (int o = 32; o > 0; o >>= 1) {
    m1 = fmaxf(m1, __shfl_down(m1, o));
    m2 = fmaxf(m2, __shfl_down(m2, o));
    m3 = fmaxf(m3, __shfl_down(m3, o));
  }
  __shared__ float s1[4], s2[4], s3[4];
  int w = threadIdx.x >> 6, l = threadIdx.x & 63;
  if (l == 0) { s1[w] = m1; s2[w] = m2; s3[w] = m3; }
  __syncthreads();
  if (threadIdx.x == 0) {
    m1 = fmaxf(fmaxf(s1[0], s1[1]), fmaxf(s1[2], s1[3]));
    m2 = fmaxf(fmaxf(s2[0], s2[1]), fmaxf(s2[2], s2[3]));
    m3 = fmaxf(fmaxf(s3[0], s3[1]), fmaxf(s3[2], s3[3]));
    atomicMax(&ws_u[OFF_SLOT1 / 4 + 0], __float_as_uint(m1));
    atomicMax(&ws_u[OFF_SLOT1 / 4 + 1], __float_as_uint(m2));
    atomicMax(&ws_u[OFF_SLOT1 / 4 + 2], __float_as_uint(m3));
  }
}

__global__ void k_sx(const int* __restrict__ ids, const float* __restrict__ emb,
                     float* sx) {
  int t = blockIdx.x, tid = threadIdx.x;
  int row = tid >> 2, qu = tid & 3;
  const float* e = emb + (size_t)ids[row * SEQ + t] * HID + qu * 128;
  float m = 0.f;
  for (int i = 0; i < 128; i++) m = fmaxf(m, fabsf(e[i]));
#pragma unroll
  for (int o = 32; o > 0; o >>= 1) m = fmaxf(m, __shfl_down(m, o));
  __shared__ float sm[4];
  if ((tid & 63) == 0) sm[tid >> 6] = m;
  __syncthreads();
  if (tid == 0) sx[t] = fmaxf(fmaxf(sm[0], sm[1]), fmaxf(sm[2], sm[3]));
}

__global__ void k_len(const int* __restrict__ mask, int* len) {
  int b = threadIdx.x;
  int s = 0;
  for (int i = 0; i < SEQ; i++) s += mask[b * SEQ + i];
  len[b] = (s + SEQ - 1) & (SEQ - 1);   // (sum-1) mod 512, jnp wrap semantics
}

__global__ void k_wf(const float* __restrict__ wi, const float* __restrict__ wh,
                     const unsigned* ws_u, v4i* wif, v4i* whf) {
  int t = blockIdx.x * 256 + threadIdx.x;          // 0..65535
  int lane = t & 63, kb = (t >> 6) & 7, nt = (t >> 9) & 1, bk = t >> 10;
  int cc = lane & 15, q = lane >> 4;
  int col = (nt * 2 + (cc >> 3)) * 512 + bk * 8 + (cc & 7);
  int k0 = kb * 64 + q * 16;
  float si = fmaxf(__uint_as_float(ws_u[OFF_SLOT1 / 4 + 0]), 1e-8f) / 127.0f;
  float sh = fmaxf(__uint_as_float(ws_u[OFF_SLOT1 / 4 + 1]), 1e-8f) / 127.0f;
  float buf[16];
#pragma unroll
  for (int j = 0; j < 16; j++) buf[j] = wi[(size_t)col * 512 + k0 + j];
  v4i o;
  o[0] = (int)packdiv(buf + 0, si);  o[1] = (int)packdiv(buf + 4, si);
  o[2] = (int)packdiv(buf + 8, si);  o[3] = (int)packdiv(buf + 12, si);
  wif[t] = o;
#pragma unroll
  for (int j = 0; j < 16; j++) buf[j] = wh[(size_t)col * 512 + k0 + j];
  o[0] = (int)packdiv(buf + 0, sh);  o[1] = (int)packdiv(buf + 4, sh);
  o[2] = (int)packdiv(buf + 8, sh);  o[3] = (int)packdiv(buf + 12, sh);
  whf[t] = o;
}

__global__ void k_xf(const int* __restrict__ ids, const float* __restrict__ emb,
                     const float* __restrict__ sx, v4i* xf) {
  int g = blockIdx.x * 256 + threadIdx.x;          // 0..1048575 == t*2048+idx
  int t = g >> 11, idx = g & 2047;
  int r = idx & 15, q = (idx >> 4) & 3, kb = (idx >> 6) & 7, m = idx >> 9;
  int row = m * 16 + r;
  int k0 = ((kb << 2) + q) << 4;
  float s = fmaxf(sx[t], 1e-8f) / 127.0f;
  const float* e = emb + (size_t)ids[row * SEQ + t] * HID + k0;
  float buf[16];
#pragma unroll
  for (int j = 0; j < 16; j++) buf[j] = e[j];
  v4i o;
  o[0] = (int)packdiv(buf + 0, s);  o[1] = (int)packdiv(buf + 4, s);
  o[2] = (int)packdiv(buf + 8, s);  o[3] = (int)packdiv(buf + 12, s);
  xf[g] = o;
}

// ------------------------------ persistent kernel ---------------------------

__global__ __launch_bounds__(NTHR) void k_main(
    char* ws, const float* __restrict__ b_inp, const float* __restrict__ b_hid,
    const float* __restrict__ lin_w, const float* __restrict__ lin_b,
    float* __restrict__ out) {
  const int tid  = threadIdx.x;
  const int bk   = blockIdx.x;
  const int lane = tid & 63;
  const int wv   = tid >> 6;
  const int nt   = wv & 1, mh = wv >> 1;
  const int mt0  = mh * 2, mt1 = mh * 2 + 1;
  const int cc   = lane & 15, qq = lane >> 4;

  unsigned* cnt   = (unsigned*)(ws + OFF_CNT);
  unsigned* slot1 = (unsigned*)(ws + OFF_SLOT1);
  unsigned* sloth = (unsigned*)(ws + OFF_SLOTH);
  unsigned* slotc = (unsigned*)(ws + OFF_SLOTC);
  const float* sxr = (const float*)(ws + OFF_SX);
  const int* lens  = (const int*)(ws + OFF_LEN);
  float* hg    = (float*)(ws + OFF_HG);
  float* hlast = (float*)(ws + OFF_HLAST);
  const v4i* wifg = (const v4i*)(ws + OFF_WIF);
  const v4i* whfg = (const v4i*)(ws + OFF_WHF);
  const v4i* xfg  = (const v4i*)(ws + OFF_XF);

  __shared__ v4i xfrag[2048];
  __shared__ v4i hfrag[2048];
  __shared__ float gl[64][33];
  __shared__ float redh[4], redc[4];

  // weight fragments -> VGPRs for the whole kernel
  v4i wif[8], whf[8];
  {
    int base = ((bk * 2 + nt) * 8) * 64 + lane;
#pragma unroll
    for (int kb = 0; kb < 8; kb++) {
      wif[kb] = wifg[base + kb * 64];
      whf[kb] = whfg[base + kb * 64];
    }
  }
  const int colg = (nt * 2 + (cc >> 3)) * 512 + bk * 8 + (cc & 7);
  const float bi = b_inp[colg], bh = b_hid[colg];
  const float swi = fmaxf(__uint_as_float(slot1[0]), 1e-8f) / 127.0f;
  const float swh = fmaxf(__uint_as_float(slot1[1]), 1e-8f) / 127.0f;

  // elementwise cell ownership: thread -> (row, 2 adjacent hidden js)
  const int erow = tid >> 2;
  const int ejj  = (tid & 3) * 2;
  const int jg0 = bk * 8 + ejj, jg1 = jg0 + 1;   // same 16-chunk always
  const int mylen = lens[erow];
  const int hoff0 = fragidx(erow, jg0 >> 4) * 16 + (jg0 & 15);
  const int hoff1 = hoff0 + 1;
  float c0 = 0.0f, c1 = 0.0f;
  float capmax = 0.0f;

  for (int t = 0; t < SEQ; ++t) {
    const float th   = fmaxf(__uint_as_float(sloth[t]), 1e-8f);
    const float shq  = th / 127.0f;
    const float invh = 127.0f / th;
    const float tc   = fmaxf(__uint_as_float(slotc[t]), 1e-8f);
    const float scq  = tc / 127.0f;
    const float invc = 127.0f / tc;
    const float sxq  = fmaxf(sxr[t], 1e-8f) / 127.0f;
    const float fx = sxq * swi;
    const float fh = shq * swh;

    const float* hr = hg + (t & 1) * (NB * HID);
    float*       hw = hg + ((t + 1) & 1) * (NB * HID);
    const v4i*   xt = xfg + t * 2048;

    // stage x (int8 frag-major) and h (fp32 -> quantize -> int8 frag-major)
#pragma unroll
    for (int i = 0; i < 8; i++) {
      int c = i * 256 + tid;
      xfrag[c] = xt[c];
      const float4* p = (const float4*)(hr + c * 16);
      float4 va = p[0], vb = p[1], vc = p[2], vd = p[3];
      v4i pk;
      pk[0] = pack4q(va, invh);
      pk[1] = pack4q(vb, invh);
      pk[2] = pack4q(vc, invh);
      pk[3] = pack4q(vd, invh);
      hfrag[c] = pk;
    }
    __syncthreads();

    // GEMM: gates[64,32-slice] = x_int8 @ Wi^T (exact) and h_int8 @ Wh^T
    v4i ax0 = {0, 0, 0, 0}, ax1 = {0, 0, 0, 0};
    v4i ah0 = {0, 0, 0, 0}, ah1 = {0, 0, 0, 0};
#pragma unroll
    for (int kb = 0; kb < 8; kb++) {
      v4i a0 = xfrag[(mt0 * 8 + kb) * 64 + lane];
      v4i a1 = xfrag[(mt1 * 8 + kb) * 64 + lane];
      v4i h0 = hfrag[(mt0 * 8 + kb) * 64 + lane];
      v4i h1 = hfrag[(mt1 * 8 + kb) * 64 + lane];
      ax0 = __builtin_amdgcn_mfma_i32_16x16x64_i8(a0, wif[kb], ax0, 0, 0, 0);
      ax1 = __builtin_amdgcn_mfma_i32_16x16x64_i8(a1, wif[kb], ax1, 0, 0, 0);
      ah0 = __builtin_amdgcn_mfma_i32_16x16x64_i8(h0, whf[kb], ah0, 0, 0, 0);
      ah1 = __builtin_amdgcn_mfma_i32_16x16x64_i8(h1, whf[kb], ah1, 0, 0, 0);
    }
    // epilogue: mirror np order ((x@WiT + b_inp) + h@WhT) + b_hid
#pragma unroll
    for (int r = 0; r < 4; r++) {
      int r0 = mt0 * 16 + qq * 4 + r;
      int r1 = mt1 * 16 + qq * 4 + r;
      float xp0 = (float)ax0[r] * fx, hp0 = (float)ah0[r] * fh;
      float xp1 = (float)ax1[r] * fx, hp1 = (float)ah1[r] * fh;
      gl[r0][nt * 16 + cc] = ((xp0 + bi) + hp0) + bh;
      gl[r1][nt * 16 + cc] = ((xp1 + bi) + hp1) + bh;
    }
    __syncthreads();

    // elementwise LSTM cell update (2 cells per thread, c in registers)
    float i0 = sigm(gl[erow][ejj]);
    float f0 = sigm(gl[erow][8 + ejj]);
    float g0 = tanhf(gl[erow][16 + ejj]);
    float o0 = sigm(gl[erow][24 + ejj]);
    float i1 = sigm(gl[erow][ejj + 1]);
    float f1 = sigm(gl[erow][8 + ejj + 1]);
    float g1 = tanhf(gl[erow][16 + ejj + 1]);
    float o1 = sigm(gl[erow][24 + ejj + 1]);
    float cq0 = rintf(c0 * invc) * scq;
    float cq1 = rintf(c1 * invc) * scq;
    float cn0 = f0 * cq0 + i0 * g0;
    float cn1 = f1 * cq1 + i1 * g1;
    float hn0 = o0 * tanhf(cn0);
    float hn1 = o1 * tanhf(cn1);
    c0 = cn0; c1 = cn1;

    hw[hoff0] = hn0;
    hw[hoff1] = hn1;
    if (t == mylen) {
      hlast[erow * HID + jg0] = hn0;
      hlast[erow * HID + jg1] = hn1;
      capmax = fmaxf(capmax, fmaxf(fabsf(hn0), fabsf(hn1)));
    }

    // block-level abs-max of new h and c, then one atomicMax per block
    float mhv = fmaxf(fabsf(hn0), fabsf(hn1));
    float mcv = fmaxf(fabsf(cn0), fabsf(cn1));
#pragma unroll
    for (int o = 32; o > 0; o >>= 1) {
      mhv = fmaxf(mhv, __shfl_down(mhv, o));
      mcv = fmaxf(mcv, __shfl_down(mcv, o));
    }
    if (lane == 0) { redh[wv] = mhv; redc[wv] = mcv; }
    __syncthreads();
    if (tid == 0) {
      float MH = fmaxf(fmaxf(redh[0], redh[1]), fmaxf(redh[2], redh[3]));
      float MC = fmaxf(fmaxf(redc[0], redc[1]), fmaxf(redc[2], redc[3]));
      atomicMax(&sloth[t + 1], __float_as_uint(MH));
      atomicMax(&slotc[t + 1], __float_as_uint(MC));
      __threadfence();   // wbl2: flush this XCD's L2 (covers block's h stores)
      __hip_atomic_fetch_add(cnt, 1u, __ATOMIC_RELEASE, __HIP_MEMORY_SCOPE_AGENT);
      unsigned tgt = (unsigned)NBLK * (unsigned)(t + 1);
      while (__hip_atomic_load(cnt, __ATOMIC_RELAXED, __HIP_MEMORY_SCOPE_AGENT) < tgt)
        __builtin_amdgcn_s_sleep(2);
    }
    __syncthreads();
    __builtin_amdgcn_fence(__ATOMIC_ACQUIRE, "agent");  // buffer_inv
  }

  // publish per-block capture max; final barrier round; block 0 does logits
#pragma unroll
  for (int o = 32; o > 0; o >>= 1) capmax = fmaxf(capmax, __shfl_down(capmax, o));
  if (lane == 0) redh[wv] = capmax;
  __syncthreads();
  if (tid == 0) {
    float CM = fmaxf(fmaxf(redh[0], redh[1]), fmaxf(redh[2], redh[3]));
    atomicMax(&slot1[3], __float_as_uint(CM));
    __threadfence();
    __hip_atomic_fetch_add(cnt, 1u, __ATOMIC_RELEASE, __HIP_MEMORY_SCOPE_AGENT);
    if (bk == 0) {
      unsigned tgt = (unsigned)NBLK * (unsigned)(SEQ + 1);
      while (__hip_atomic_load(cnt, __ATOMIC_RELAXED, __HIP_MEMORY_SCOPE_AGENT) < tgt)
        __builtin_amdgcn_s_sleep(2);
    }
  }
  __syncthreads();
  if (bk != 0) return;
  __builtin_amdgcn_fence(__ATOMIC_ACQUIRE, "agent");

  {
    float tHL = fmaxf(__uint_as_float(slot1[3]), 1e-8f);
    float sHL = tHL / 127.0f, invHL = 127.0f / tHL;
    float tLW = fmaxf(__uint_as_float(slot1[2]), 1e-8f);
    float sLW = tLW / 127.0f, invLW = 127.0f / tLW;
    int b = tid & 63, quarter = tid >> 6;
    const float* hl = hlast + b * HID;
    float acc = 0.0f;
    for (int j = quarter * 128; j < quarter * 128 + 128; ++j) {
      float hq = rintf(hl[j] * invHL) * sHL;
      float wq = rintf(lin_w[j] * invLW) * sLW;
      acc += hq * wq;
    }
    float* fl = &gl[0][0];
    fl[tid] = acc;
    __syncthreads();
    if (tid < 64) {
      float s = fl[tid] + fl[64 + tid] + fl[128 + tid] + fl[192 + tid];
      out[tid] = s + lin_b[0];
    }
  }
}

// --------------------------------- launch -----------------------------------

extern "C" void kernel_launch(void* const* d_in, const int* in_sizes, int n_in,
                              void* d_out, int out_size, void* d_ws, size_t ws_size,
                              hipStream_t stream) {
  const int*   ids  = (const int*)d_in[0];
  const int*   mask = (const int*)d_in[1];
  const float* emb  = (const float*)d_in[2];
  const float* wi   = (const float*)d_in[3];
  const float* wh   = (const float*)d_in[4];
  const float* binp = (const float*)d_in[5];
  const float* bhid = (const float*)d_in[6];
  const float* lw   = (const float*)d_in[7];
  const float* lb   = (const float*)d_in[8];
  char* ws = (char*)d_ws;
  float* out = (float*)d_out;
  (void)in_sizes; (void)n_in; (void)out_size; (void)ws_size;

  hipMemsetAsync(ws, 0, ZERO_BYTES, stream);
  k_maxw<<<256, 256, 0, stream>>>(wi, wh, lw, (unsigned*)ws);
  k_sx<<<SEQ, 256, 0, stream>>>(ids, emb, (float*)(ws + OFF_SX));
  k_len<<<1, 64, 0, stream>>>(mask, (int*)(ws + OFF_LEN));
  k_wf<<<256, 256, 0, stream>>>(wi, wh, (const unsigned*)ws,
                                (v4i*)(ws + OFF_WIF), (v4i*)(ws + OFF_WHF));
  k_xf<<<4096, 256, 0, stream>>>(ids, emb, (const float*)(ws + OFF_SX),
                                 (v4i*)(ws + OFF_XF));
  k_main<<<NBLK, NTHR, 0, stream>>>(ws, binp, bhid, lw, lb, out);
}